// Round 3
// baseline (154.245 us; speedup 1.0000x reference)
//
#include <hip/hip_runtime.h>
#include <hip/hip_bf16.h>

#define VOCAB 50000
#define HID   256
#define BATCH 512
#define GH    768   // 3*H

typedef __attribute__((ext_vector_type(8))) __bf16 bf16x8;
typedef __attribute__((ext_vector_type(4))) float f32x4;
typedef __attribute__((ext_vector_type(4))) unsigned int u32x4;

union BFrag {
    bf16x8 v;
    u32x4  q;
    unsigned short u[8];
};

__device__ __forceinline__ unsigned short f2bf(float f) {
    unsigned int x = __builtin_bit_cast(unsigned int, f);
    x += 0x7FFFu + ((x >> 16) & 1u);          // round-to-nearest-even
    return (unsigned short)(x >> 16);
}

__device__ __forceinline__ float fast_sigmoid(float x) {
    return 1.0f / (1.0f + __expf(-x));
}
__device__ __forceinline__ float fast_tanh(float x) {
    return 1.0f - 2.0f / (1.0f + __expf(2.0f * x));
}

// Convert two f32x4 (8 consecutive f32) into one bf16x8 fragment.
__device__ __forceinline__ void cvt8(BFrag& t, f32x4 lo, f32x4 hi) {
    t.u[0] = f2bf(lo.x); t.u[1] = f2bf(lo.y);
    t.u[2] = f2bf(lo.z); t.u[3] = f2bf(lo.w);
    t.u[4] = f2bf(hi.x); t.u[5] = f2bf(hi.y);
    t.u[6] = f2bf(hi.z); t.u[7] = f2bf(hi.w);
}

// C[M x Ncols] = A[M x 256] @ Bm[Ncols x 256]^T  (both K-major, K=256, no K-loop)
// Barrier-free: no LDS. B row kept in registers (8 frags); A fragments loaded
// directly global->VGPR (A is tiny and L2-resident).
// EPI  0: raw f32 store            1: tanh(acc + bias[col]), nontemporal store
// ASRC 0: A is f32 (convert)       1: A is bf16 (ushort)
// NTB  1: nontemporal B loads (each B row read by exactly one block)
// Block: 256 threads (4 waves). BN=64 cols/block (wave w owns cols w*16..w*16+15).
template <int EPI, int ASRC, int NTB>
__global__ __launch_bounds__(256) void gemm_nt(
    const void* __restrict__ Asrc, const float* __restrict__ Bm,
    float* __restrict__ C, const float* __restrict__ bias,
    int Ncols, int mChunks)
{
    const int tid  = threadIdx.x;
    const int wid  = tid >> 6;
    const int lane = tid & 63;
    const int r    = lane & 15;               // fragment row/col index
    const int g    = lane >> 4;               // k-group
    const int col  = blockIdx.x * 64 + wid * 16 + r;   // output column == B row
    const int bcol = col < Ncols ? col : (Ncols - 1);

    // ---- load B fragments once, convert f32 -> bf16, keep in registers ----
    BFrag bf[8];
    {
        const f32x4* wrow = reinterpret_cast<const f32x4*>(Bm + (size_t)bcol * 256);
        #pragma unroll
        for (int kk = 0; kk < 8; kk++) {
            f32x4 lo, hi;
            if (NTB) {
                lo = __builtin_nontemporal_load(&wrow[kk * 8 + g * 2]);
                hi = __builtin_nontemporal_load(&wrow[kk * 8 + g * 2 + 1]);
            } else {
                lo = wrow[kk * 8 + g * 2];
                hi = wrow[kk * 8 + g * 2 + 1];
            }
            cvt8(bf[kk], lo, hi);
        }
    }
    float biasv = 0.0f;
    if (EPI == 1) biasv = bias[bcol];

    for (int c = 0; c < mChunks; c++) {
        const int mbase = (blockIdx.y * mChunks + c) * 64;

        f32x4 acc[4];
        #pragma unroll
        for (int m = 0; m < 4; m++) acc[m] = (f32x4){0.f, 0.f, 0.f, 0.f};

        #pragma unroll
        for (int kk = 0; kk < 8; kk++) {
            #pragma unroll
            for (int m = 0; m < 4; m++) {
                const int arow = mbase + m * 16 + r;
                BFrag a;
                if (ASRC == 1) {
                    const u32x4* ap = reinterpret_cast<const u32x4*>(
                        (const unsigned short*)Asrc + (size_t)arow * 256);
                    a.q = ap[kk * 4 + g];
                } else {
                    const f32x4* ap = reinterpret_cast<const f32x4*>(
                        (const float*)Asrc + (size_t)arow * 256);
                    cvt8(a, ap[kk * 8 + g * 2], ap[kk * 8 + g * 2 + 1]);
                }
                acc[m] = __builtin_amdgcn_mfma_f32_16x16x32_bf16(a.v, bf[kk].v, acc[m], 0, 0, 0);
            }
        }

        // ---- epilogue ----
        if (col < Ncols) {
            #pragma unroll
            for (int m = 0; m < 4; m++) {
                #pragma unroll
                for (int j = 0; j < 4; j++) {
                    int row = mbase + m * 16 + g * 4 + j;
                    float v = acc[m][j];
                    if (EPI == 1) {
                        v = fast_tanh(v + biasv);
                        __builtin_nontemporal_store(v, &C[(size_t)row * Ncols + col]);
                    } else {
                        C[(size_t)row * Ncols + col] = v;
                    }
                }
            }
        }
    }
}

// GRU gates: x-gather from w_ih + gate math. One block per batch row, thread = k.
__global__ __launch_bounds__(256) void gru_gate(
    const int* __restrict__ inp, const float* __restrict__ hidden,
    const float* __restrict__ w_ih, const float* __restrict__ b_ih,
    const float* __restrict__ b_hh, const float* __restrict__ hproj,
    float* __restrict__ h1out, unsigned short* __restrict__ h1bf)
{
    const int b = blockIdx.x;
    const int k = threadIdx.x;
    const int c = inp[b];

    float xr = w_ih[(size_t)k * VOCAB + c]         + b_ih[k];
    float xz = w_ih[(size_t)(k + 256) * VOCAB + c] + b_ih[k + 256];
    float xn = w_ih[(size_t)(k + 512) * VOCAB + c] + b_ih[k + 512];

    float hr = hproj[b * GH + k]       + b_hh[k];
    float hz = hproj[b * GH + 256 + k] + b_hh[k + 256];
    float hn = hproj[b * GH + 512 + k] + b_hh[k + 512];

    float rg = fast_sigmoid(xr + hr);
    float zg = fast_sigmoid(xz + hz);
    float ng = fast_tanh(xn + rg * hn);
    float h0 = hidden[b * HID + k];
    float h1 = (1.0f - zg) * ng + zg * h0;

    h1out[b * HID + k] = h1;
    h1bf[b * HID + k]  = f2bf(h1);
}

extern "C" void kernel_launch(void* const* d_in, const int* in_sizes, int n_in,
                              void* d_out, int out_size, void* d_ws, size_t ws_size,
                              hipStream_t stream) {
    const int*   input  = (const int*)  d_in[0];
    // d_in[1] = target (unused)
    const float* hidden = (const float*)d_in[2];
    const float* w_ih   = (const float*)d_in[3];
    const float* w_hh   = (const float*)d_in[4];
    const float* b_ih   = (const float*)d_in[5];
    const float* b_hh   = (const float*)d_in[6];
    const float* w_out  = (const float*)d_in[7];
    const float* b_out  = (const float*)d_in[8];

    float* logit = (float*)d_out;                            // [512, 50000]
    float* h1    = (float*)d_out + (size_t)BATCH * VOCAB;    // [512, 256]

    float*          hproj = (float*)d_ws;                                   // 512*768 f32
    unsigned short* h1bf  = (unsigned short*)((char*)d_ws + (size_t)BATCH * GH * 4);

    // K1: hproj = h0 @ w_hh^T   (512 x 768, K=256)
    dim3 g1(GH / 64, BATCH / 64);           // (12, 8), mChunks = 1
    gemm_nt<0, 0, 0><<<g1, 256, 0, stream>>>(hidden, w_hh, hproj, nullptr, GH, 1);

    // K2: gates -> h1 (f32 into d_out tail, bf16 into ws)
    gru_gate<<<BATCH, 256, 0, stream>>>(input, hidden, w_ih, b_ih, b_hh, hproj, h1, h1bf);

    // K3: logit = tanh(h1 @ w_out^T + b_out)   (512 x 50000, K=256)
    dim3 g3((VOCAB + 63) / 64, 1);          // 782 blocks, all co-resident
    gemm_nt<1, 1, 1><<<g3, 256, 0, stream>>>(h1bf, w_out, logit, b_out, VOCAB, 8);
}

// Round 4
// 65.906 us; speedup vs baseline: 2.3404x; 2.3404x over previous
//
#include <hip/hip_runtime.h>
#include <hip/hip_bf16.h>

#define VOCAB 50000
#define HID   256
#define BATCH 512
#define GH    768   // 3*H

typedef __attribute__((ext_vector_type(8))) __bf16 bf16x8;
typedef __attribute__((ext_vector_type(4))) float f32x4;
typedef __attribute__((ext_vector_type(4))) unsigned int u32x4;

union BFrag {
    bf16x8 v;
    u32x4  q;
    unsigned short u[8];
};

__device__ __forceinline__ unsigned short f2bf(float f) {
    unsigned int x = __builtin_bit_cast(unsigned int, f);
    x += 0x7FFFu + ((x >> 16) & 1u);          // round-to-nearest-even
    return (unsigned short)(x >> 16);
}

__device__ __forceinline__ float fast_sigmoid(float x) {
    return 1.0f / (1.0f + __expf(-x));
}
__device__ __forceinline__ float fast_tanh(float x) {
    return 1.0f - 2.0f / (1.0f + __expf(2.0f * x));
}

__device__ __forceinline__ void cvt8(BFrag& t, f32x4 lo, f32x4 hi) {
    t.u[0] = f2bf(lo.x); t.u[1] = f2bf(lo.y);
    t.u[2] = f2bf(lo.z); t.u[3] = f2bf(lo.w);
    t.u[4] = f2bf(hi.x); t.u[5] = f2bf(hi.y);
    t.u[6] = f2bf(hi.z); t.u[7] = f2bf(hi.w);
}

// C[M x Ncols] = A[M x 256] @ Bm[Ncols x 256]^T  (K=256 entirely, no K-loop)
// B row in registers; A staged through double-buffered, XOR-swizzled LDS.
// Schedule per chunk: ds_write(cur) ; barrier ; store(prev acc) ;
//                     issue global loads(next) ; ds_read+MFMA(cur).
// -> one barrier/chunk; at each barrier the pending vmem ops all had a full
//    chunk of compute to complete (no cold drain).
// EPI 0: raw f32 store   1: tanh(acc + bias[col])
// ASRC 0: A is f32       1: A is bf16
template <int EPI, int ASRC>
__global__ __launch_bounds__(256) void gemm_nt(
    const void* __restrict__ Asrc, const float* __restrict__ Bm,
    float* __restrict__ C, const float* __restrict__ bias,
    int Ncols, int mChunks)
{
    __shared__ char ldsA[2][64 * 512];        // 2 x (64 rows x 256 bf16), swizzled

    const int tid  = threadIdx.x;
    const int wid  = tid >> 6;
    const int lane = tid & 63;
    const int r    = lane & 15;               // fragment row/col index
    const int g    = lane >> 4;               // k-group
    const int col  = blockIdx.x * 64 + wid * 16 + r;
    const int bcol = col < Ncols ? col : (Ncols - 1);

    // ---- B fragments: load once, convert, keep in registers ----
    BFrag bf[8];
    {
        const f32x4* wrow = reinterpret_cast<const f32x4*>(Bm + (size_t)bcol * 256);
        #pragma unroll
        for (int kk = 0; kk < 8; kk++)
            cvt8(bf[kk], wrow[kk * 8 + g * 2], wrow[kk * 8 + g * 2 + 1]);
    }
    float biasv = 0.0f;
    if (EPI == 1) biasv = bias[bcol];

    // ---- staging helpers ----
    u32x4 streg[8];                           // in-flight chunk (reg-staged)
    auto load_chunk = [&](int c) {            // global -> regs (coalesced)
        const int mbase = (blockIdx.y * mChunks + c) * 64;
        if (ASRC == 1) {
            const u32x4* src = reinterpret_cast<const u32x4*>(
                (const unsigned short*)Asrc + (size_t)mbase * 256);
            #pragma unroll
            for (int i = 0; i < 8; i++) streg[i] = src[tid + i * 256];
        } else {
            const f32x4* src = reinterpret_cast<const f32x4*>(
                (const float*)Asrc + (size_t)mbase * 256);
            #pragma unroll
            for (int i = 0; i < 8; i++) {
                int u = tid + i * 256;
                BFrag t; cvt8(t, src[2 * u], src[2 * u + 1]);
                streg[i] = t.q;
            }
        }
    };
    auto write_lds = [&](int buf) {           // regs -> swizzled LDS
        #pragma unroll
        for (int i = 0; i < 8; i++) {
            int u = tid + i * 256;
            int row = u >> 5, c16 = u & 31;
            int byte = (row * 512 + c16 * 16) ^ ((row & 7) << 4);
            *reinterpret_cast<u32x4*>(&ldsA[buf][byte]) = streg[i];
        }
    };
    auto compute = [&](int buf, f32x4 (&acc)[4]) {
        #pragma unroll
        for (int m = 0; m < 4; m++) acc[m] = (f32x4){0.f, 0.f, 0.f, 0.f};
        #pragma unroll
        for (int kk = 0; kk < 8; kk++) {
            #pragma unroll
            for (int m = 0; m < 4; m++) {
                int arow = m * 16 + r;
                int byte = (arow * 512 + kk * 64 + g * 16) ^ ((arow & 7) << 4);
                BFrag a;
                a.q = *reinterpret_cast<const u32x4*>(&ldsA[buf][byte]);
                acc[m] = __builtin_amdgcn_mfma_f32_16x16x32_bf16(a.v, bf[kk].v, acc[m], 0, 0, 0);
            }
        }
    };
    auto store_c = [&](int c, f32x4 (&acc)[4]) {
        if (col >= Ncols) return;
        const int mbase = (blockIdx.y * mChunks + c) * 64;
        #pragma unroll
        for (int m = 0; m < 4; m++) {
            #pragma unroll
            for (int j = 0; j < 4; j++) {
                int row = mbase + m * 16 + g * 4 + j;
                float v = acc[m][j];
                if (EPI == 1) v = fast_tanh(v + biasv);
                C[(size_t)row * Ncols + col] = v;
            }
        }
    };

    f32x4 accA[4], accB[4];                   // statically-indexed double acc
    load_chunk(0);

    for (int c = 0; c < mChunks; c += 2) {
        // --- even chunk: compute into accA, store accB (chunk c-1) ---
        write_lds(c & 1);
        __syncthreads();
        if (c > 0) store_c(c - 1, accB);
        if (c + 1 < mChunks) load_chunk(c + 1);
        compute(c & 1, accA);

        if (c + 1 < mChunks) {
            // --- odd chunk: compute into accB, store accA (chunk c) ---
            write_lds((c + 1) & 1);
            __syncthreads();
            store_c(c, accA);
            if (c + 2 < mChunks) load_chunk(c + 2);
            compute((c + 1) & 1, accB);
        }
    }
    if (mChunks & 1) store_c(mChunks - 1, accA);
    else             store_c(mChunks - 1, accB);
}

// GRU gates: x-gather from w_ih + gate math. One block per batch row, thread = k.
__global__ __launch_bounds__(256) void gru_gate(
    const int* __restrict__ inp, const float* __restrict__ hidden,
    const float* __restrict__ w_ih, const float* __restrict__ b_ih,
    const float* __restrict__ b_hh, const float* __restrict__ hproj,
    float* __restrict__ h1out, unsigned short* __restrict__ h1bf)
{
    const int b = blockIdx.x;
    const int k = threadIdx.x;
    const int c = inp[b];

    float xr = w_ih[(size_t)k * VOCAB + c]         + b_ih[k];
    float xz = w_ih[(size_t)(k + 256) * VOCAB + c] + b_ih[k + 256];
    float xn = w_ih[(size_t)(k + 512) * VOCAB + c] + b_ih[k + 512];

    float hr = hproj[b * GH + k]       + b_hh[k];
    float hz = hproj[b * GH + 256 + k] + b_hh[k + 256];
    float hn = hproj[b * GH + 512 + k] + b_hh[k + 512];

    float rg = fast_sigmoid(xr + hr);
    float zg = fast_sigmoid(xz + hz);
    float ng = fast_tanh(xn + rg * hn);
    float h0 = hidden[b * HID + k];
    float h1 = (1.0f - zg) * ng + zg * h0;

    h1out[b * HID + k] = h1;
    h1bf[b * HID + k]  = f2bf(h1);
}

extern "C" void kernel_launch(void* const* d_in, const int* in_sizes, int n_in,
                              void* d_out, int out_size, void* d_ws, size_t ws_size,
                              hipStream_t stream) {
    const int*   input  = (const int*)  d_in[0];
    // d_in[1] = target (unused)
    const float* hidden = (const float*)d_in[2];
    const float* w_ih   = (const float*)d_in[3];
    const float* w_hh   = (const float*)d_in[4];
    const float* b_ih   = (const float*)d_in[5];
    const float* b_hh   = (const float*)d_in[6];
    const float* w_out  = (const float*)d_in[7];
    const float* b_out  = (const float*)d_in[8];

    float* logit = (float*)d_out;                            // [512, 50000]
    float* h1    = (float*)d_out + (size_t)BATCH * VOCAB;    // [512, 256]

    float*          hproj = (float*)d_ws;                                   // 512*768 f32
    unsigned short* h1bf  = (unsigned short*)((char*)d_ws + (size_t)BATCH * GH * 4);

    // K1: hproj = h0 @ w_hh^T   (512 x 768, K=256)
    dim3 g1(GH / 64, BATCH / 64);           // (12, 8), mChunks = 1
    gemm_nt<0, 0><<<g1, 256, 0, stream>>>(hidden, w_hh, hproj, nullptr, GH, 1);

    // K2: gates -> h1 (f32 into d_out tail, bf16 into ws)
    gru_gate<<<BATCH, 256, 0, stream>>>(input, hidden, w_ih, b_ih, b_hh, hproj, h1, h1bf);

    // K3: logit = tanh(h1 @ w_out^T + b_out)   (512 x 50000, K=256)
    dim3 g3((VOCAB + 63) / 64, 1);          // 782 blocks, mChunks = 8
    gemm_nt<1, 1><<<g3, 256, 0, stream>>>(h1bf, w_out, logit, b_out, VOCAB, 8);
}